// Round 19
// baseline (2144.356 us; speedup 1.0000x reference)
//
#include <hip/hip_runtime.h>
#include <hip/hip_bf16.h>
#include <stdint.h>

// E60bGatedResidualCell — R19: R17 + clean retry queues (wave-role vmem split).
// out[t] = h²σ(h); h_{t+1} = h_t + g_t ⊙ tanh(h_t W_hᵀ + x_t W_xᵀ + b)
// fp32 outputs. P in out_h[t+1], G in out_o[t] (read-ahead, pre-overwrite).
// h exchange (R17, proven): h_ex[8 grp][16 slot][4][1024] f32 NaN-gated, sc1.
// NEW: tid<128 = sync path only (retry 8 granules + scatter + reduce + sc1 h
// store) — their vmcnt(0) never waits on HBM. tid>=128 = all HBM ops (P/G
// prefetch issue at end of step, drain at top of next step; PO/PH stores;
// NaN pre-clear), handed off via Pbuf/Gbuf/hout LDS with a 3rd barrier.
// 256 WGs = 8 groups (4 b) × 32 e-slices, 1 WG/CU (R18 proved 2/CU contends).

#define T_DIM 512
#define B_DIM 32
#define D_DIM 1024
#define M_DIM (T_DIM*B_DIM)
#define NANB 0x7FC00000u

typedef __attribute__((ext_vector_type(4))) float f32x4;
typedef __attribute__((ext_vector_type(4))) int   i32x4;
typedef __attribute__((ext_vector_type(8))) short bf16x8;

__device__ inline unsigned short f2b(float f){
  union { float f; uint32_t u; } c; c.f = f;
  uint32_t u = c.u + 0x7fffu + ((c.u >> 16) & 1u);   // RNE
  return (unsigned short)(u >> 16);
}
__device__ inline float b2f(unsigned short h){
  union { uint32_t u; float f; } c; c.u = ((uint32_t)h) << 16;
  return c.f;
}

// ---- init: out_h[0]=0; h_ex slot0=0 (h0), slots1..15=NaN marker (all groups) --
__global__ void init_kernel(float* __restrict__ out_h0, uint32_t* __restrict__ h_ex){
  int i = blockIdx.x*blockDim.x + threadIdx.x;       // 0..524287
  if (i < 32768) out_h0[i] = 0.f;
  int slot = (i >> 12) & 15;                         // [g][slot][4096]
  h_ex[i] = (slot == 0) ? 0u : NANB;
}

// ---- proj (split-bf16 MFMA, fp32 out): OUT[m,n] = f(sum_k X[m,k]*W[n,k]+bias) -
template<int MODE>
__global__ __launch_bounds__(256, 2)
void proj_m(const float* __restrict__ X, const float* __restrict__ W,
            const float* __restrict__ bias, float* __restrict__ OUT)
{
  __shared__ unsigned short Ah[128*64];
  __shared__ unsigned short Al[128*64];
  __shared__ unsigned short Bh[128*64];
  __shared__ unsigned short Bl[128*64];
  char* AhB=(char*)Ah; char* AlB=(char*)Al; char* BhB=(char*)Bh; char* BlB=(char*)Bl;
  const int tid  = threadIdx.x;
  const int lane = tid & 63;
  const int wave = tid >> 6;
  const int m0 = blockIdx.y * 128;
  const int n0 = blockIdx.x * 128;
  const int wm = (wave >> 1) * 64;
  const int wn = (wave & 1) * 64;
  const int fr = lane & 15;
  const int fq = lane >> 4;

  f32x4 acc[4][4];
  #pragma unroll
  for (int i=0;i<4;++i)
    #pragma unroll
    for (int j=0;j<4;++j) acc[i][j] = (f32x4){0.f,0.f,0.f,0.f};

  for (int kt = 0; kt < D_DIM/64; ++kt) {
    #pragma unroll
    for (int c = 0; c < 4; ++c) {
      int idx = tid + c*256;
      int row = idx >> 3;
      int k8  = idx & 7;
      const float* ga = X + (size_t)(m0+row)*D_DIM + kt*64 + k8*8;
      const float* gb = W + (size_t)(n0+row)*D_DIM + kt*64 + k8*8;
      f32x4 a0 = *(const f32x4*)ga, a1 = *(const f32x4*)(ga+4);
      f32x4 b0 = *(const f32x4*)gb, b1 = *(const f32x4*)(gb+4);
      bf16x8 vah, val, vbh, vbl;
      #pragma unroll
      for (int j=0;j<4;++j){
        unsigned short h;
        h = f2b(a0[j]); vah[j]   = (short)h; val[j]   = (short)f2b(a0[j]-b2f(h));
        h = f2b(a1[j]); vah[4+j] = (short)h; val[4+j] = (short)f2b(a1[j]-b2f(h));
        h = f2b(b0[j]); vbh[j]   = (short)h; vbl[j]   = (short)f2b(b0[j]-b2f(h));
        h = f2b(b1[j]); vbh[4+j] = (short)h; vbl[4+j] = (short)f2b(b1[j]-b2f(h));
      }
      int lb = row*128 + ((k8*16) ^ ((row&7)<<4));
      *(bf16x8*)(AhB + lb) = vah;
      *(bf16x8*)(AlB + lb) = val;
      *(bf16x8*)(BhB + lb) = vbh;
      *(bf16x8*)(BlB + lb) = vbl;
    }
    __syncthreads();
    #pragma unroll
    for (int kk=0; kk<2; ++kk) {
      bf16x8 afh[4], afl[4], bfh[4], bfl[4];
      #pragma unroll
      for (int i=0;i<4;++i){
        int row = wm+i*16+fr;
        int off = row*128 + ((kk*64 + fq*16) ^ ((row&7)<<4));
        afh[i] = *(const bf16x8*)(AhB + off);
        afl[i] = *(const bf16x8*)(AlB + off);
      }
      #pragma unroll
      for (int j=0;j<4;++j){
        int row = wn+j*16+fr;
        int off = row*128 + ((kk*64 + fq*16) ^ ((row&7)<<4));
        bfh[j] = *(const bf16x8*)(BhB + off);
        bfl[j] = *(const bf16x8*)(BlB + off);
      }
      #pragma unroll
      for (int i=0;i<4;++i)
        #pragma unroll
        for (int j=0;j<4;++j){
          acc[i][j] = __builtin_amdgcn_mfma_f32_16x16x32_bf16(afh[i], bfh[j], acc[i][j], 0,0,0);
          acc[i][j] = __builtin_amdgcn_mfma_f32_16x16x32_bf16(afh[i], bfl[j], acc[i][j], 0,0,0);
          acc[i][j] = __builtin_amdgcn_mfma_f32_16x16x32_bf16(afl[i], bfh[j], acc[i][j], 0,0,0);
        }
    }
    __syncthreads();
  }
  #pragma unroll
  for (int j=0;j<4;++j) {
    int col = n0 + wn + j*16 + fr;
    float bv = bias[col];
    #pragma unroll
    for (int i=0;i<4;++i) {
      int rowb = m0 + wm + i*16 + fq*4;
      #pragma unroll
      for (int r=0;r<4;++r) {
        float v = acc[i][j][r] + bv;
        if (MODE==1) v = 1.f/(1.f + expf(-v));
        OUT[(size_t)(rowb+r)*D_DIM + col] = v;
      }
    }
  }
}

// ---- persistent recurrence ----------------------------------------------------
__global__ __launch_bounds__(256, 1)
void rnn_persist(const float* __restrict__ Wh,
                 float* PO,                 // out_o: G (read) / out (write)
                 float* PH,                 // out_h: P (read@t+1 slot) / h (write)
                 float* __restrict__ h_ex)  // [8 grp][16 slot][4096 f32]
{
  __shared__ char  hsb[4*4096];          // h staged, XOR-swizzled 16B granules (16KB)
  __shared__ float part[16*137];         // k-partials, padded stride (8.8KB)
  __shared__ float hout[128];            // hn hand-off w0/w1 -> w2/w3 (512B)
  __shared__ float Pbuf[128];            // P hand-off w2/w3 -> w0/w1 (512B)
  __shared__ float Gbuf[128];            // G hand-off (512B)

  const int tid = threadIdx.x;
  const int blk = blockIdx.x;
  const int g   = blk & 7;               // chain-group 0..7 (XCD-interleaved)
  const int sl  = blk >> 3;              // e-slice 0..31
  const int e0  = sl * 32;
  const int b0  = g * 4;
  const int e2  = tid & 15;              // e-pair 0..15
  const int kc  = tid >> 4;              // k-chunk 0..15 (64 k each)

  // ---- one-time: Wh slice into registers (2 e-cols x 64 k per thread) ----
  f32x4 wh0[16], wh1[16];
  {
    const f32x4* wp0 = (const f32x4*)(Wh + (size_t)(e0 + 2*e2 + 0)*D_DIM + kc*64);
    const f32x4* wp1 = (const f32x4*)(Wh + (size_t)(e0 + 2*e2 + 1)*D_DIM + kc*64);
    #pragma unroll
    for (int i = 0; i < 16; ++i) { wh0[i] = wp0[i]; wh1[i] = wp1[i]; }
  }

  const int bl = tid >> 5;               // tid<128 epilogue role: b 0..3
  const int el = tid & 31;               // e 0..31
  const int j2 = tid - 128;              // tid>=128 role index 0..127
  const int bl2 = (j2 >> 5) & 3;
  const int el2 = j2 & 31;
  float hold = 0.f;                      // tid<128: own h[b0+bl][e0+el]

  // prologue: w2/w3 issue P/G loads for t=0 (drained at top of t=0)
  float Pld = 0.f, Gld = 0.f;
  if (tid >= 128) {
    size_t idx0 = (size_t)(b0 + bl2)*D_DIM + e0 + el2;
    const float* pp = PH + idx0 + 32768;
    const float* gp = PO + idx0;
    asm volatile("global_load_dword %0, %1, off" : "=v"(Pld) : "v"(pp) : "memory");
    asm volatile("global_load_dword %0, %1, off" : "=v"(Gld) : "v"(gp) : "memory");
  }

  for (int t = 0; t < T_DIM; ++t) {

    if (tid < 128) {
      // ---- sync path: retry 8 granules of h_ex[g][t&15] (queue: only 1 sc1
      // store from last epilogue -> vmcnt(0) is a fast MALL ACK, no HBM)
      const char* hsrc = (const char*)(h_ex + ((size_t)g*16 + (t & 15))*4096) + tid*16;
      i32x4 r0, r1, r2, r3, r4, r5, r6, r7;
      while (true) {
        asm volatile("global_load_dwordx4 %0, %1, off sc1" : "=v"(r0) : "v"(hsrc)         : "memory");
        asm volatile("global_load_dwordx4 %0, %1, off sc1" : "=v"(r1) : "v"(hsrc + 2048)  : "memory");
        asm volatile("global_load_dwordx4 %0, %1, off sc1" : "=v"(r2) : "v"(hsrc + 4096)  : "memory");
        asm volatile("global_load_dwordx4 %0, %1, off sc1" : "=v"(r3) : "v"(hsrc + 6144)  : "memory");
        asm volatile("global_load_dwordx4 %0, %1, off sc1" : "=v"(r4) : "v"(hsrc + 8192)  : "memory");
        asm volatile("global_load_dwordx4 %0, %1, off sc1" : "=v"(r5) : "v"(hsrc + 10240) : "memory");
        asm volatile("global_load_dwordx4 %0, %1, off sc1" : "=v"(r6) : "v"(hsrc + 12288) : "memory");
        asm volatile("global_load_dwordx4 %0, %1, off sc1" : "=v"(r7) : "v"(hsrc + 14336) : "memory");
        asm volatile("s_waitcnt vmcnt(0)" ::: "memory");
        __builtin_amdgcn_sched_barrier(0);
        bool ok = (r0[0]!=(int)NANB)&(r0[1]!=(int)NANB)&(r0[2]!=(int)NANB)&(r0[3]!=(int)NANB)
                & (r1[0]!=(int)NANB)&(r1[1]!=(int)NANB)&(r1[2]!=(int)NANB)&(r1[3]!=(int)NANB)
                & (r2[0]!=(int)NANB)&(r2[1]!=(int)NANB)&(r2[2]!=(int)NANB)&(r2[3]!=(int)NANB)
                & (r3[0]!=(int)NANB)&(r3[1]!=(int)NANB)&(r3[2]!=(int)NANB)&(r3[3]!=(int)NANB)
                & (r4[0]!=(int)NANB)&(r4[1]!=(int)NANB)&(r4[2]!=(int)NANB)&(r4[3]!=(int)NANB)
                & (r5[0]!=(int)NANB)&(r5[1]!=(int)NANB)&(r5[2]!=(int)NANB)&(r5[3]!=(int)NANB)
                & (r6[0]!=(int)NANB)&(r6[1]!=(int)NANB)&(r6[2]!=(int)NANB)&(r6[3]!=(int)NANB)
                & (r7[0]!=(int)NANB)&(r7[1]!=(int)NANB)&(r7[2]!=(int)NANB)&(r7[3]!=(int)NANB);
        if (ok) break;
        __builtin_amdgcn_s_sleep(2);
      }
      // scatter: load l -> plane l>>1, granule g16 = tid + (l&1)*128, swizzled
      #pragma unroll
      for (int l = 0; l < 8; ++l) {
        int plane = l >> 1;
        int g16   = tid + ((l & 1) << 7);
        int g16s  = g16 ^ (g16 >> 4);
        i32x4 v = (l==0)?r0:(l==1)?r1:(l==2)?r2:(l==3)?r3:(l==4)?r4:(l==5)?r5:(l==6)?r6:r7;
        *(i32x4*)(hsb + plane*4096 + g16s*16) = v;
      }
    } else {
      // ---- HBM path: drain last step's issued ops, publish P/G to LDS
      asm volatile("s_waitcnt vmcnt(0)" ::: "memory");
      __builtin_amdgcn_sched_barrier(0);
      Pbuf[j2] = Pld;
      Gbuf[j2] = Gld;
    }
    __syncthreads();   // B1: hsb + Pbuf/Gbuf ready

    // compute: all 256 threads, acc[b][u] over 64-k chunk (conflict-free reads)
    float acc[4][2];
    #pragma unroll
    for (int b = 0; b < 4; ++b) { acc[b][0] = 0.f; acc[b][1] = 0.f; }
    #pragma unroll
    for (int i = 0; i < 16; ++i) {
      f32x4 w0 = wh0[i], w1 = wh1[i];
      #pragma unroll
      for (int b = 0; b < 4; ++b) {
        f32x4 hv = *(const f32x4*)(hsb + b*4096 + kc*256 + ((i ^ kc) << 4));
        float d0 = hv[0]*w0[0] + hv[1]*w0[1] + hv[2]*w0[2] + hv[3]*w0[3];
        float d1 = hv[0]*w1[0] + hv[1]*w1[1] + hv[2]*w1[2] + hv[3]*w1[3];
        acc[b][0] += d0;
        acc[b][1] += d1;
      }
    }
    #pragma unroll
    for (int b = 0; b < 4; ++b) {
      part[kc*137 + b*32 + 2*e2 + 0] = acc[b][0];
      part[kc*137 + b*32 + 2*e2 + 1] = acc[b][1];
    }
    __syncthreads();   // B2: part ready

    // reduce + exchange (tid<128 only; queue stays HBM-free)
    if (tid < 128) {
      float pre = 0.f;
      #pragma unroll
      for (int q = 0; q < 16; ++q) pre += part[q*137 + bl*32 + el];
      pre += Pbuf[tid];
      float th = tanhf(pre);
      float hn = hold + Gbuf[tid]*th;
      hold = hn;
      float* hdst = h_ex + ((size_t)g*16 + ((t+1) & 15))*4096 + (size_t)bl*1024 + e0 + el;
      asm volatile("global_store_dword %0, %1, off sc1" :: "v"(hdst), "v"(hn) : "memory");
      hout[tid] = hn;
    }
    __syncthreads();   // B3: hout ready

    // HBM path (tid>=128): outputs, pre-clear, next prefetch — all off-chain
    if (tid >= 128) {
      float hn = hout[j2];
      if (t + 1 < T_DIM) {
        size_t idx_n = (size_t)(t+1)*32768 + (size_t)(b0 + bl2)*D_DIM + e0 + el2;
        const float* pp = PH + idx_n + 32768;
        const float* gp = PO + idx_n;
        asm volatile("global_load_dword %0, %1, off" : "=v"(Pld) : "v"(pp) : "memory");
        asm volatile("global_load_dword %0, %1, off" : "=v"(Gld) : "v"(gp) : "memory");
      }
      float sg = 1.f/(1.f + expf(-hn));
      size_t idx2 = (size_t)t*32768 + (size_t)(b0 + bl2)*D_DIM + e0 + el2;
      PO[idx2] = hn*hn*sg;               // out[t]
      PH[idx2 + 32768] = hn;             // h[t+1] (overwrites P slot)
      uint32_t nanb = NANB;
      float* ndst = h_ex + ((size_t)g*16 + ((t+9) & 15))*4096 + (size_t)bl2*1024 + e0 + el2;
      asm volatile("global_store_dword %0, %1, off sc1" :: "v"(ndst), "v"(nanb) : "memory");
    }
  }
}

extern "C" void kernel_launch(void* const* d_in, const int* in_sizes, int n_in,
                              void* d_out, int out_size, void* d_ws, size_t ws_size,
                              hipStream_t stream) {
  const float* x  = (const float*)d_in[0];
  const float* Wh = (const float*)d_in[1];
  const float* Wx = (const float*)d_in[2];
  const float* Wg = (const float*)d_in[3];
  const float* b  = (const float*)d_in[4];
  const float* bg = (const float*)d_in[5];

  float* out_o = (float*)d_out;                       // [T,B,D] fp32
  float* out_h = out_o + (size_t)M_DIM*D_DIM;         // [T+1,B,D] fp32

  float* h_ex = (float*)d_ws;                         // 8*16*16KB = 2 MB

  init_kernel<<<2048, 256, 0, stream>>>(out_h, (uint32_t*)h_ex);
  proj_m<1><<<dim3(8,128), 256, 0, stream>>>(x, Wg, bg, out_o);           // G -> out_o[t]
  proj_m<0><<<dim3(8,128), 256, 0, stream>>>(x, Wx, b,  out_h + 32768);   // P -> out_h[t+1]
  rnn_persist<<<256, 256, 0, stream>>>(Wh, out_o, out_h, h_ex);
}

// Round 20
// 1647.931 us; speedup vs baseline: 1.3012x; 1.3012x over previous
//
#include <hip/hip_runtime.h>
#include <hip/hip_bf16.h>
#include <stdint.h>

// E60bGatedResidualCell — R20 = R17 (champion, restored verbatim).
// out[t] = h²σ(h); h_{t+1} = h_t + g_t ⊙ tanh(h_t W_hᵀ + x_t W_xᵀ + b)
// fp32 outputs. P in out_h[t+1] (read@t+1-ahead prefetch, pre-overwrite),
// G in out_o[t] (same). h exchange: d_ws h_ex[8 grp][16 slot][4][1024] f32,
// init: slot0=h0=0, slots1..15=0x7FC00000 marker. Producers store h (sc1) to
// slot (t+1)&15 and pre-clear their float in slot (t+9)&15 (consumed >=8 steps
// ago by lockstep induction). Consumers retry-load granules until != marker.
// No flags, no producer vmcnt/barrier. 2 barriers/step (hsb, part).
// Structural probes measured and rejected: 2 WG/CU (R18, −10%, MALL
// contention), wave-role vmem split (R19, −33%, extra barrier + half-width
// retry), tagged-u64 (R13, −25%, 2x exchange bytes), system-vs-agent scope
// (R14, neutral), LDS re-tiling (R12, −12%, serial reduce lengthens chain).

#define T_DIM 512
#define B_DIM 32
#define D_DIM 1024
#define M_DIM (T_DIM*B_DIM)
#define NANB 0x7FC00000u

typedef __attribute__((ext_vector_type(4))) float f32x4;
typedef __attribute__((ext_vector_type(4))) int   i32x4;
typedef __attribute__((ext_vector_type(8))) short bf16x8;

__device__ inline unsigned short f2b(float f){
  union { float f; uint32_t u; } c; c.f = f;
  uint32_t u = c.u + 0x7fffu + ((c.u >> 16) & 1u);   // RNE
  return (unsigned short)(u >> 16);
}
__device__ inline float b2f(unsigned short h){
  union { uint32_t u; float f; } c; c.u = ((uint32_t)h) << 16;
  return c.f;
}

// ---- init: out_h[0]=0; h_ex slot0=0, slots1..15=NaN marker (all groups) ------
__global__ void init_kernel(float* __restrict__ out_h0, uint32_t* __restrict__ h_ex){
  int i = blockIdx.x*blockDim.x + threadIdx.x;       // 0..524287
  if (i < 32768) out_h0[i] = 0.f;
  int slot = (i >> 12) & 15;                         // [g][slot][4096]
  h_ex[i] = (slot == 0) ? 0u : NANB;
}

// ---- proj (split-bf16 MFMA, fp32 out): OUT[m,n] = f(sum_k X[m,k]*W[n,k]+bias) -
template<int MODE>
__global__ __launch_bounds__(256, 2)
void proj_m(const float* __restrict__ X, const float* __restrict__ W,
            const float* __restrict__ bias, float* __restrict__ OUT)
{
  __shared__ unsigned short Ah[128*64];
  __shared__ unsigned short Al[128*64];
  __shared__ unsigned short Bh[128*64];
  __shared__ unsigned short Bl[128*64];
  char* AhB=(char*)Ah; char* AlB=(char*)Al; char* BhB=(char*)Bh; char* BlB=(char*)Bl;
  const int tid  = threadIdx.x;
  const int lane = tid & 63;
  const int wave = tid >> 6;
  const int m0 = blockIdx.y * 128;
  const int n0 = blockIdx.x * 128;
  const int wm = (wave >> 1) * 64;
  const int wn = (wave & 1) * 64;
  const int fr = lane & 15;
  const int fq = lane >> 4;

  f32x4 acc[4][4];
  #pragma unroll
  for (int i=0;i<4;++i)
    #pragma unroll
    for (int j=0;j<4;++j) acc[i][j] = (f32x4){0.f,0.f,0.f,0.f};

  for (int kt = 0; kt < D_DIM/64; ++kt) {
    #pragma unroll
    for (int c = 0; c < 4; ++c) {
      int idx = tid + c*256;
      int row = idx >> 3;
      int k8  = idx & 7;
      const float* ga = X + (size_t)(m0+row)*D_DIM + kt*64 + k8*8;
      const float* gb = W + (size_t)(n0+row)*D_DIM + kt*64 + k8*8;
      f32x4 a0 = *(const f32x4*)ga, a1 = *(const f32x4*)(ga+4);
      f32x4 b0 = *(const f32x4*)gb, b1 = *(const f32x4*)(gb+4);
      bf16x8 vah, val, vbh, vbl;
      #pragma unroll
      for (int j=0;j<4;++j){
        unsigned short h;
        h = f2b(a0[j]); vah[j]   = (short)h; val[j]   = (short)f2b(a0[j]-b2f(h));
        h = f2b(a1[j]); vah[4+j] = (short)h; val[4+j] = (short)f2b(a1[j]-b2f(h));
        h = f2b(b0[j]); vbh[j]   = (short)h; vbl[j]   = (short)f2b(b0[j]-b2f(h));
        h = f2b(b1[j]); vbh[4+j] = (short)h; vbl[4+j] = (short)f2b(b1[j]-b2f(h));
      }
      int lb = row*128 + ((k8*16) ^ ((row&7)<<4));
      *(bf16x8*)(AhB + lb) = vah;
      *(bf16x8*)(AlB + lb) = val;
      *(bf16x8*)(BhB + lb) = vbh;
      *(bf16x8*)(BlB + lb) = vbl;
    }
    __syncthreads();
    #pragma unroll
    for (int kk=0; kk<2; ++kk) {
      bf16x8 afh[4], afl[4], bfh[4], bfl[4];
      #pragma unroll
      for (int i=0;i<4;++i){
        int row = wm+i*16+fr;
        int off = row*128 + ((kk*64 + fq*16) ^ ((row&7)<<4));
        afh[i] = *(const bf16x8*)(AhB + off);
        afl[i] = *(const bf16x8*)(AlB + off);
      }
      #pragma unroll
      for (int j=0;j<4;++j){
        int row = wn+j*16+fr;
        int off = row*128 + ((kk*64 + fq*16) ^ ((row&7)<<4));
        bfh[j] = *(const bf16x8*)(BhB + off);
        bfl[j] = *(const bf16x8*)(BlB + off);
      }
      #pragma unroll
      for (int i=0;i<4;++i)
        #pragma unroll
        for (int j=0;j<4;++j){
          acc[i][j] = __builtin_amdgcn_mfma_f32_16x16x32_bf16(afh[i], bfh[j], acc[i][j], 0,0,0);
          acc[i][j] = __builtin_amdgcn_mfma_f32_16x16x32_bf16(afh[i], bfl[j], acc[i][j], 0,0,0);
          acc[i][j] = __builtin_amdgcn_mfma_f32_16x16x32_bf16(afl[i], bfh[j], acc[i][j], 0,0,0);
        }
    }
    __syncthreads();
  }
  #pragma unroll
  for (int j=0;j<4;++j) {
    int col = n0 + wn + j*16 + fr;
    float bv = bias[col];
    #pragma unroll
    for (int i=0;i<4;++i) {
      int rowb = m0 + wm + i*16 + fq*4;
      #pragma unroll
      for (int r=0;r<4;++r) {
        float v = acc[i][j][r] + bv;
        if (MODE==1) v = 1.f/(1.f + expf(-v));
        OUT[(size_t)(rowb+r)*D_DIM + col] = v;
      }
    }
  }
}

// ---- persistent recurrence ----------------------------------------------------
__global__ __launch_bounds__(256, 1)
void rnn_persist(const float* __restrict__ Wh,
                 float* PO,                 // out_o: G (read) / out (write)
                 float* PH,                 // out_h: P (read@t+1 slot) / h (write)
                 float* __restrict__ h_ex)  // [8 grp][16 slot][4096 f32]
{
  __shared__ char  hsb[4*4096];          // h staged, XOR-swizzled 16B granules (16KB)
  __shared__ float part[16*137];         // k-partials, padded stride (8.8KB)

  const int tid = threadIdx.x;
  const int blk = blockIdx.x;
  const int g   = blk & 7;               // chain-group 0..7 (XCD-interleaved)
  const int sl  = blk >> 3;              // e-slice 0..31
  const int e0  = sl * 32;
  const int b0  = g * 4;
  const int e2  = tid & 15;              // e-pair 0..15
  const int kc  = tid >> 4;              // k-chunk 0..15 (64 k each)

  // ---- one-time: Wh slice into registers (2 e-cols x 64 k per thread) ----
  f32x4 wh0[16], wh1[16];
  {
    const f32x4* wp0 = (const f32x4*)(Wh + (size_t)(e0 + 2*e2 + 0)*D_DIM + kc*64);
    const f32x4* wp1 = (const f32x4*)(Wh + (size_t)(e0 + 2*e2 + 1)*D_DIM + kc*64);
    #pragma unroll
    for (int i = 0; i < 16; ++i) { wh0[i] = wp0[i]; wh1[i] = wp1[i]; }
  }

  const int bl = tid >> 5;               // epilogue roles (tid<128): b 0..3
  const int el = tid & 31;               // e 0..31
  float hold = 0.f;                      // this thread's own h[b0+bl][e0+el]

  // prefetch P/G for t=0
  float Pv = 0.f, Gv = 0.f;
  if (tid < 128) {
    size_t idx0 = (size_t)(b0 + bl)*D_DIM + e0 + el;
    Pv = PH[idx0 + 32768];
    Gv = PO[idx0];
  }

  for (int t = 0; t < T_DIM; ++t) {
    size_t idx_out = (size_t)t*32768 + (size_t)(b0 + bl)*D_DIM + e0 + el;

    // stage h[4][1024] from h_ex[g][t&15] — NaN-marker-gated retry (sc1)
    // R13-proven shape: unconditional reloads, waitcnt, sched_barrier(0) (rule #18)
    {
      const char* hsrc = (const char*)(h_ex + ((size_t)g*16 + (t & 15))*4096) + tid*16;
      i32x4 r0, r1, r2, r3;
      while (true) {
        asm volatile("global_load_dwordx4 %0, %1, off sc1" : "=v"(r0) : "v"(hsrc)         : "memory");
        asm volatile("global_load_dwordx4 %0, %1, off sc1" : "=v"(r1) : "v"(hsrc + 4096)  : "memory");
        asm volatile("global_load_dwordx4 %0, %1, off sc1" : "=v"(r2) : "v"(hsrc + 8192)  : "memory");
        asm volatile("global_load_dwordx4 %0, %1, off sc1" : "=v"(r3) : "v"(hsrc + 12288) : "memory");
        asm volatile("s_waitcnt vmcnt(0)" ::: "memory");
        __builtin_amdgcn_sched_barrier(0);
        bool ok = (r0[0]!=(int)NANB) & (r0[1]!=(int)NANB) & (r0[2]!=(int)NANB) & (r0[3]!=(int)NANB)
                & (r1[0]!=(int)NANB) & (r1[1]!=(int)NANB) & (r1[2]!=(int)NANB) & (r1[3]!=(int)NANB)
                & (r2[0]!=(int)NANB) & (r2[1]!=(int)NANB) & (r2[2]!=(int)NANB) & (r2[3]!=(int)NANB)
                & (r3[0]!=(int)NANB) & (r3[1]!=(int)NANB) & (r3[2]!=(int)NANB) & (r3[3]!=(int)NANB);
        if (ok) break;
        __builtin_amdgcn_s_sleep(2);
      }
      // scatter to LDS with XOR swizzle: granule g16 -> g16 ^ (g16>>4), per b-plane
      #pragma unroll
      for (int i = 0; i < 4; ++i) {
        int g16s = tid ^ (tid >> 4);
        i32x4 v = (i==0) ? r0 : (i==1) ? r1 : (i==2) ? r2 : r3;
        *(i32x4*)(hsb + i*4096 + g16s*16) = v;
      }
    }
    __syncthreads();

    // prefetch P/G for t+1 — lands during compute, off the sync chain
    float Pn = 0.f, Gn = 0.f;
    if (t + 1 < T_DIM && tid < 128) {
      size_t idx_n = (size_t)(t+1)*32768 + (size_t)(b0 + bl)*D_DIM + e0 + el;
      Pn = PH[idx_n + 32768];
      Gn = PO[idx_n];
    }

    // compute: acc[b][u] = sum over this thread's 64-k chunk (conflict-free reads)
    float acc[4][2];
    #pragma unroll
    for (int b = 0; b < 4; ++b) { acc[b][0] = 0.f; acc[b][1] = 0.f; }
    #pragma unroll
    for (int i = 0; i < 16; ++i) {
      f32x4 w0 = wh0[i], w1 = wh1[i];
      #pragma unroll
      for (int b = 0; b < 4; ++b) {
        f32x4 hv = *(const f32x4*)(hsb + b*4096 + kc*256 + ((i ^ kc) << 4));
        float d0 = hv[0]*w0[0] + hv[1]*w0[1] + hv[2]*w0[2] + hv[3]*w0[3];
        float d1 = hv[0]*w1[0] + hv[1]*w1[1] + hv[2]*w1[2] + hv[3]*w1[3];
        acc[b][0] += d0;
        acc[b][1] += d1;
      }
    }
    #pragma unroll
    for (int b = 0; b < 4; ++b) {
      part[kc*137 + b*32 + 2*e2 + 0] = acc[b][0];
      part[kc*137 + b*32 + 2*e2 + 1] = acc[b][1];
    }
    __syncthreads();

    // reduce + epilogue (tid<128: one (b,e) each)
    if (tid < 128) {
      float pre = 0.f;
      #pragma unroll
      for (int q = 0; q < 16; ++q) pre += part[q*137 + bl*32 + el];
      pre += Pv;
      float th = tanhf(pre);
      float hn = hold + Gv*th;
      hold = hn;
      float sg = 1.f/(1.f + expf(-hn));
      // 1) exchange store: h -> h_ex[g][(t+1)&15] (sc1; data IS the flag)
      float* hdst = h_ex + ((size_t)g*16 + ((t+1) & 15))*4096 + (size_t)bl*1024 + e0 + el;
      asm volatile("global_store_dword %0, %1, off sc1" :: "v"(hdst), "v"(hn) : "memory");
      // 2) pre-clear my float in slot (t+9)&15 (consumed >=8 steps ago)
      uint32_t nanb = NANB;
      float* ndst = h_ex + ((size_t)g*16 + ((t+9) & 15))*4096 + (size_t)bl*1024 + e0 + el;
      asm volatile("global_store_dword %0, %1, off sc1" :: "v"(ndst), "v"(nanb) : "memory");
      // 3) outputs (plain stores, off the chain)
      PH[idx_out + 32768] = hn;            // h[t+1] (overwrites P slot)
      PO[idx_out] = hn*hn*sg;              // out[t]
    }
    Pv = Pn; Gv = Gn;
    // no trailing barrier/vmcnt/flag — consumers gate on the data itself
  }
}

extern "C" void kernel_launch(void* const* d_in, const int* in_sizes, int n_in,
                              void* d_out, int out_size, void* d_ws, size_t ws_size,
                              hipStream_t stream) {
  const float* x  = (const float*)d_in[0];
  const float* Wh = (const float*)d_in[1];
  const float* Wx = (const float*)d_in[2];
  const float* Wg = (const float*)d_in[3];
  const float* b  = (const float*)d_in[4];
  const float* bg = (const float*)d_in[5];

  float* out_o = (float*)d_out;                       // [T,B,D] fp32
  float* out_h = out_o + (size_t)M_DIM*D_DIM;         // [T+1,B,D] fp32

  float* h_ex = (float*)d_ws;                         // 8*16*16KB = 2 MB

  init_kernel<<<2048, 256, 0, stream>>>(out_h, (uint32_t*)h_ex);
  proj_m<1><<<dim3(8,128), 256, 0, stream>>>(x, Wg, bg, out_o);           // G -> out_o[t]
  proj_m<0><<<dim3(8,128), 256, 0, stream>>>(x, Wx, b,  out_h + 32768);   // P -> out_h[t+1]
  rnn_persist<<<256, 256, 0, stream>>>(Wh, out_o, out_h, h_ex);
}